// Round 16
// baseline (607.716 us; speedup 1.0000x reference)
//
#include <hip/hip_runtime.h>
#include <hip/hip_bf16.h>
#include <float.h>
#include <math.h>

#define BB 4
#define N1 4096
#define NT 8192
#define CH 128
#define NBRS 18
#define ZSEL 2.35f
#define EQ 4096.0f
#define GQGAP 6
#define GQCOV 3

typedef __attribute__((ext_vector_type(8))) short s16x8;
typedef __attribute__((ext_vector_type(16))) float f32x16;
typedef __attribute__((ext_vector_type(4))) float f32x4;

__device__ inline unsigned short f2bf(float v) {
  unsigned u = __float_as_uint(v);
  unsigned r = (u + 0x7FFFu + ((u >> 16) & 1u)) >> 16;
  return (unsigned short)r;
}
__device__ inline float bf2f(unsigned short h) {
  return __uint_as_float((unsigned)h << 16);
}
__device__ inline unsigned mapf(float f) {
  unsigned u = __float_as_uint(f);
  return (u & 0x80000000u) ? ~u : (u | 0x80000000u);
}
__device__ inline float gelu_f(float x) {
  return 0.5f * x * (1.0f + erff(x * 0.70710678118654752f));
}

#define INS12U(l, key0)                         \
  {                                             \
    unsigned nk = key0;                         \
    _Pragma("unroll")                           \
    for (int j = 0; j < 12; ++j) {              \
      bool sw = nk > l[j];                      \
      unsigned tv = l[j];                       \
      l[j] = sw ? nk : tv;                      \
      nk = sw ? tv : nk;                        \
    }                                           \
  }

// --------------------------------------------- split f32 weights -> hi/lo bf16
__global__ __launch_bounds__(256) void wsplit_k(const float* __restrict__ w,
                                                unsigned short* __restrict__ hi,
                                                unsigned short* __restrict__ lo,
                                                int n) {
  int t = blockIdx.x * 256 + threadIdx.x;
  if (t < n) {
    float v = w[t];
    unsigned short h = f2bf(v);
    float r = v - bf2f(h);
    hi[t] = h; lo[t] = f2bf(r);
  }
}

// ------------------------------------------------- concat x,y + squared norms
__global__ __launch_bounds__(256) void norms_concat_k(const float* __restrict__ x,
                                                      const float* __restrict__ y,
                                                      float* __restrict__ xy,
                                                      float* __restrict__ norms) {
  int w = (blockIdx.x * 256 + threadIdx.x) >> 6;
  int lane = threadIdx.x & 63;
  int b = w >> 13, row = w & 8191;
  const float* src = (row < N1) ? (x + ((size_t)b * N1 + row) * CH)
                                : (y + ((size_t)b * N1 + (row - N1)) * CH);
  float2 v = *(const float2*)(src + lane * 2);
  *(float2*)(xy + (size_t)w * CH + lane * 2) = v;
  float s = v.x * v.x + v.y * v.y;
  for (int off = 32; off > 0; off >>= 1) s += __shfl_down(s, off);
  if (lane == 0) norms[w] = s;
}

// ---------------------------------------- build split-bf16 k-major candidate buf
__global__ __launch_bounds__(256) void cbt_k(const float* __restrict__ xy,
                                             unsigned short* __restrict__ cbt) {
  int t = blockIdx.x * 256 + threadIdx.x;
  int u = t >> 15, p = t & 32767;
  const float* src = xy + (size_t)p * CH + u * 8;
  unsigned hw[4], lw[4];
#pragma unroll
  for (int j = 0; j < 4; ++j) {
    float v0 = src[2 * j], v1 = src[2 * j + 1];
    unsigned short h0 = f2bf(v0), h1 = f2bf(v1);
    float r0 = v0 - bf2f(h0);
    float r1 = v1 - bf2f(h1);
    unsigned short l0 = f2bf(r0), l1 = f2bf(r1);
    hw[j] = (unsigned)h0 | ((unsigned)h1 << 16);
    lw[j] = (unsigned)l0 | ((unsigned)l1 << 16);
  }
  *(uint4*)&cbt[((size_t)u * 32768 + p) * 8] = make_uint4(hw[0], hw[1], hw[2], hw[3]);
  *(uint4*)&cbt[((size_t)(u + 16) * 32768 + p) * 8] = make_uint4(lw[0], lw[1], lw[2], lw[3]);
}

// ------ knn9: MFMA + per-lane sorted register top-12 (best-k), LDS 33.5 KB ->
// 4 blocks/CU for pipe overlap. In-kernel 2-list merge + certify tail.
__global__ __launch_bounds__(256) void knn9_k(const unsigned short* __restrict__ cbt,
                                              const float* __restrict__ norms,
                                              int* __restrict__ nbr,
                                              int* __restrict__ cntg,
                                              unsigned* __restrict__ listA,
                                              unsigned* __restrict__ listB,
                                              unsigned short* __restrict__ fbl) {
  __shared__ unsigned short __align__(16) cst[2][32][32][8];  // 32.8 KB
  __shared__ float cn_s[2][32];
  __shared__ unsigned short cnt2[128][2];
  const int tid = threadIdx.x;
  const int qblk = blockIdx.x, z = blockIdx.y;
  const int b = z >> 2, combo = z & 3;
  const int qoff = (combo <= 1) ? 0 : N1;
  const int coff = (combo == 0 || combo == 3) ? 0 : N1;
  const int w = tid >> 6;
  const int cl = tid & 31;
  const int h = (tid >> 5) & 1;
  const int h4 = 4 * h;
  const int ql = w * 32 + cl;
  const int q = qblk * 128 + ql;
  const size_t qp = (size_t)b * NT + qoff + q;
  const size_t cb0 = (size_t)b * NT + coff;

  const s16x8* cv = (const s16x8*)cbt;
  s16x8 bh[8], bl[8];
#pragma unroll
  for (int s = 0; s < 8; ++s) {
    bh[s] = cv[(size_t)(2 * s + h) * 32768 + qp];
    bl[s] = cv[(size_t)(16 + 2 * s + h) * 32768 + qp];
  }

  const float nq = norms[qp];
  const float Tc = 128.f - ZSEL * sqrtf(256.f + 4.f * nq);
  int cnt = 0;
  unsigned lA[12];
#pragma unroll
  for (int j = 0; j < 12; ++j) lA[j] = 0u;

  const int su = tid >> 5, sc = tid & 31;
  const char* p0 = (const char*)&cbt[((size_t)(su) * 32768 + cb0 + sc) * 8];
  const char* p1 = (const char*)&cbt[((size_t)(8 + su) * 32768 + cb0 + sc) * 8];
  const char* p2 = (const char*)&cbt[((size_t)(16 + su) * 32768 + cb0 + sc) * 8];
  const char* p3 = (const char*)&cbt[((size_t)(24 + su) * 32768 + cb0 + sc) * 8];
  const float* pn = norms + cb0 + tid;

  uint4 st[4]; float cnreg = 0.f;
  st[0] = *(const uint4*)p0; p0 += 512;
  st[1] = *(const uint4*)p1; p1 += 512;
  st[2] = *(const uint4*)p2; p2 += 512;
  st[3] = *(const uint4*)p3; p3 += 512;
  if (tid < 32) { cnreg = *pn; pn += 32; }
  *(uint4*)&cst[0][su][sc][0] = st[0];
  *(uint4*)&cst[0][8 + su][sc][0] = st[1];
  *(uint4*)&cst[0][16 + su][sc][0] = st[2];
  *(uint4*)&cst[0][24 + su][sc][0] = st[3];
  if (tid < 32) cn_s[0][tid] = cnreg;
  __syncthreads();

  int buf = 0;
  for (int t = 0; t < 128; ++t) {
    if (t < 127) {
      st[0] = *(const uint4*)p0; p0 += 512;
      st[1] = *(const uint4*)p1; p1 += 512;
      st[2] = *(const uint4*)p2; p2 += 512;
      st[3] = *(const uint4*)p3; p3 += 512;
      if (tid < 32) { cnreg = *pn; pn += 32; }
    }
    f32x16 acc = {0.f,0.f,0.f,0.f,0.f,0.f,0.f,0.f,0.f,0.f,0.f,0.f,0.f,0.f,0.f,0.f};
#pragma unroll
    for (int s = 0; s < 8; ++s) {
      s16x8 a0 = *(const s16x8*)&cst[buf][2 * s + h][cl][0];
      s16x8 a1 = *(const s16x8*)&cst[buf][16 + 2 * s + h][cl][0];
      acc = __builtin_amdgcn_mfma_f32_32x32x16_bf16(a0, bh[s], acc, 0, 0, 0);
      acc = __builtin_amdgcn_mfma_f32_32x32x16_bf16(a0, bl[s], acc, 0, 0, 0);
      acc = __builtin_amdgcn_mfma_f32_32x32x16_bf16(a1, bh[s], acc, 0, 0, 0);
    }
    float4 c0 = *(const float4*)&cn_s[buf][h4];
    float4 c1 = *(const float4*)&cn_s[buf][8 + h4];
    float4 c2 = *(const float4*)&cn_s[buf][16 + h4];
    float4 c3 = *(const float4*)&cn_s[buf][24 + h4];
    const float cw[16] = {c0.x, c0.y, c0.z, c0.w, c1.x, c1.y, c1.z, c1.w,
                          c2.x, c2.y, c2.z, c2.w, c3.x, c3.y, c3.z, c3.w};
    const int ib = t * 32 + h4;
#pragma unroll
    for (int r = 0; r < 16; ++r) {
      const int idx = ib + (r & 3) + 8 * (r >> 2);
      float s = fmaf(-2.0f, acc[r], cw[r]);
      if (s <= Tc) {
        ++cnt;
        int e = (int)((Tc - s) * EQ);
        e = e > 0xFFFFF ? 0xFFFFF : e;
        unsigned key = ((unsigned)e << 12) | (unsigned)(4095 - idx);
        if (key > lA[11]) INS12U(lA, key);
      }
    }
    if (t < 127) {
      *(uint4*)&cst[buf ^ 1][su][sc][0] = st[0];
      *(uint4*)&cst[buf ^ 1][8 + su][sc][0] = st[1];
      *(uint4*)&cst[buf ^ 1][16 + su][sc][0] = st[2];
      *(uint4*)&cst[buf ^ 1][24 + su][sc][0] = st[3];
      if (tid < 32) cn_s[buf ^ 1][tid] = cnreg;
    }
    __syncthreads();
    buf ^= 1;
  }

  // ---- dump reg lists into dead cst LDS: dmp[128][2][12] u32 (12 KB)
  unsigned* dmp = (unsigned*)&cst[0][0][0][0];
#pragma unroll
  for (int j = 0; j < 12; ++j) dmp[((size_t)ql * 2 + h) * 12 + j] = lA[j];
  cnt2[ql][h] = (unsigned short)(cnt > 65535 ? 65535 : cnt);
  __syncthreads();

  // ---- certify tail: thread t<128 merges the two sorted lists for query t
  if (tid < 128) {
    const int mq = tid;
    const int gq = z * 4096 + qblk * 128 + mq;
    const int c0 = cnt2[mq][0], c1 = cnt2[mq][1];
    const int k0 = c0 > 12 ? 12 : c0, k1 = c1 > 12 ? 12 : c1;
    const int m_true = c0 + c1;
    const unsigned* pa = &dmp[((size_t)mq * 2 + 0) * 12];
    const unsigned* pb = &dmp[((size_t)mq * 2 + 1) * 12];
    unsigned mg[10];
    int i = 0, j = 0;
#pragma unroll
    for (int s = 0; s < 10; ++s) {
      unsigned av = pa[i], bv = pb[j];
      bool ta = av >= bv;
      mg[s] = ta ? av : bv;
      if (ta) ++i; else ++j;
    }
    const unsigned e8 = mg[8] >> 12, e9 = mg[9] >> 12;
    const bool cov = (m_true >= 9) && (e8 >= GQCOV);
    const bool gapok = (m_true == 9) || ((e8 - e9) >= GQGAP);
    unsigned emink = 0xFFFFFFFFu;
    if (c0 > 12) emink = pa[11] >> 12;
    if (c1 > 12) { unsigned e = pb[11] >> 12; if (e < emink) emink = e; }
    const bool slok = (emink == 0xFFFFFFFFu) || (emink + 6 <= e8);

    const int qg = qblk * 128 + mq;
    const int row = (combo <= 1) ? qg : (N1 + qg);
    const int slot = (combo == 0 || combo == 2) ? 0 : 9;
    const int ioff = (combo == 1 || combo == 2) ? N1 : 0;
    int* dst = nbr + ((size_t)b * NT + row) * NBRS + slot;
    if (cov && gapok) {
#pragma unroll
      for (int s = 0; s < 9; ++s)
        dst[s] = (int)(4095u - (mg[s] & 0xFFFu)) + ioff;
    } else if (!cov || !slok) {
      int idx = atomicAdd(&cntg[1], 1);
      listB[idx] = (unsigned)gq;
    } else {
      int idx = atomicAdd(&cntg[0], 1);
      listA[idx] = ((unsigned)(k0 + k1) << 16) | (unsigned)gq;
      unsigned short* fp = fbl + (size_t)gq * 24;
      int p = 0;
      for (int t2 = 0; t2 < k0; ++t2) fp[p++] = (unsigned short)(4095u - (pa[t2] & 0xFFFu));
      for (int t2 = 0; t2 < k1; ++t2) fp[p++] = (unsigned short)(4095u - (pb[t2] & 0xFFFu));
    }
  }
}

// ------- rerank_sl: grid-stride over compacted shortlist queries (wave each)
__global__ __launch_bounds__(256) void rerank_sl_k(const float* __restrict__ xy,
                                                   const float* __restrict__ norms,
                                                   const unsigned short* __restrict__ fbl,
                                                   const unsigned* __restrict__ listA,
                                                   const int* __restrict__ cntg,
                                                   int* __restrict__ nbr) {
  const int lane = threadIdx.x & 63;
  const int wv = threadIdx.x >> 6;
  const int nA = cntg[0];
  for (int i = blockIdx.x * 4 + wv; i < nA; i += gridDim.x * 4) {
    const unsigned ent = listA[i];
    const int gq = (int)(ent & 0xffffu);
    const int m = (int)(ent >> 16);
    const int z = gq >> 12, q = gq & 4095;
    const int b = z >> 2, combo = z & 3;
    const int qoff = (combo <= 1) ? 0 : N1;
    const int coff = (combo == 0 || combo == 3) ? 0 : N1;
    const size_t cq = (size_t)b * NT + coff;
    const int row = (combo <= 1) ? q : (N1 + q);
    const int slot = (combo == 0 || combo == 2) ? 0 : 9;
    const int ioff = (combo == 1 || combo == 2) ? N1 : 0;
    int* dst = nbr + ((size_t)b * NT + row) * NBRS + slot;
    const float* qrow = xy + ((size_t)b * NT + qoff + q) * CH;

    int ci = 0; float de = FLT_MAX;
    if (lane < m) {
      ci = (int)fbl[(size_t)gq * 24 + lane];
      const float* crow = xy + (cq + ci) * CH;
      const float cnv = norms[cq + ci];
      float a0 = 0.f, a1 = 0.f, a2 = 0.f, a3 = 0.f;
#pragma unroll
      for (int k = 0; k < 32; ++k) {
        float4 qv = *(const float4*)(qrow + k * 4);
        float4 cv2 = *(const float4*)(crow + k * 4);
        a0 = fmaf(qv.x, cv2.x, a0); a1 = fmaf(qv.y, cv2.y, a1);
        a2 = fmaf(qv.z, cv2.z, a2); a3 = fmaf(qv.w, cv2.w, a3);
      }
      de = cnv - 2.0f * ((a0 + a1) + (a2 + a3));
    }
    unsigned long long key = ((unsigned long long)mapf(de) << 32) | (unsigned)ci;
    if (lane >= m) key = ~0ull;
    int xr = 0;
#pragma unroll 1
    for (int k = 0; k < m; ++k) {
      unsigned long long kk = __shfl(key, k);
      xr += (kk < key) ? 1 : 0;
    }
    if (lane < m && xr < 9) dst[xr] = ci + ioff;
  }
}

// ------- rerank_fs: grid-stride over full-scan queries (one BLOCK each)
__global__ __launch_bounds__(256) void rerank_fs_k(const float* __restrict__ xy,
                                                   const float* __restrict__ norms,
                                                   const unsigned* __restrict__ listB,
                                                   const int* __restrict__ cntg,
                                                   int* __restrict__ nbr) {
  __shared__ unsigned long long ms[4][576];
  __shared__ unsigned long long wk[36];
  const int tid = threadIdx.x;
  const int lane = tid & 63, wv = tid >> 6;
  const int nB = cntg[1];
  for (int i = blockIdx.x; i < nB; i += gridDim.x) {
    const int gq = (int)listB[i];
    const int z = gq >> 12, q = gq & 4095;
    const int b = z >> 2, combo = z & 3;
    const int qoff = (combo <= 1) ? 0 : N1;
    const int coff = (combo == 0 || combo == 3) ? 0 : N1;
    const size_t cq = (size_t)b * NT + coff;
    const int row = (combo <= 1) ? q : (N1 + q);
    const int slot = (combo == 0 || combo == 2) ? 0 : 9;
    const int ioff = (combo == 1 || combo == 2) ? N1 : 0;
    int* dst = nbr + ((size_t)b * NT + row) * NBRS + slot;
    const float* qrow = xy + ((size_t)b * NT + qoff + q) * CH;

    unsigned long long bl9[9];
#pragma unroll
    for (int j = 0; j < 9; ++j) bl9[j] = ~0ull;
    for (int it = 0; it < 16; ++it) {
      const int cc = (it * 4 + wv) * 64 + lane;
      const float* crow = xy + (cq + cc) * CH;
      float a0 = 0.f, a1 = 0.f, a2 = 0.f, a3 = 0.f;
#pragma unroll
      for (int k = 0; k < 32; ++k) {
        float4 qv = *(const float4*)(qrow + k * 4);
        float4 cv2 = *(const float4*)(crow + k * 4);
        a0 = fmaf(qv.x, cv2.x, a0); a1 = fmaf(qv.y, cv2.y, a1);
        a2 = fmaf(qv.z, cv2.z, a2); a3 = fmaf(qv.w, cv2.w, a3);
      }
      float d2v = norms[cq + cc] - 2.0f * ((a0 + a1) + (a2 + a3));
      unsigned long long key = ((unsigned long long)mapf(d2v) << 32) | (unsigned)cc;
      if (key < bl9[8]) {
#pragma unroll
        for (int jj = 0; jj < 9; ++jj) {
          bool sw = key < bl9[jj];
          unsigned long long tv = bl9[jj];
          bl9[jj] = sw ? key : tv;
          key = sw ? tv : key;
        }
      }
    }
#pragma unroll
    for (int s = 0; s < 9; ++s) ms[wv][lane * 9 + s] = bl9[s];
    int ptr = 0;
    for (int s = 0; s < 9; ++s) {
      unsigned long long hd = ms[wv][lane * 9 + ptr];
      unsigned long long mn = hd;
#pragma unroll
      for (int off = 1; off < 64; off <<= 1) {
        unsigned long long ot = __shfl_xor(mn, off);
        mn = (ot < mn) ? ot : mn;
      }
      unsigned long long wm = __ballot(hd == mn);
      int wl = __ffsll(wm) - 1;
      if (lane == wl) ptr++;
      if (lane == 0) wk[wv * 9 + s] = mn;
    }
    __syncthreads();
    if (wv == 0) {
      unsigned long long key = (lane < 36) ? wk[lane] : ~0ull;
      int xr = 0;
#pragma unroll 1
      for (int k = 0; k < 36; ++k) {
        unsigned long long kk = __shfl(key, k);
        xr += (kk < key) ? 1 : 0;
      }
      if (lane < 36 && xr < 9) dst[xr] = (int)(unsigned)(key & 0xffffffffull) + ioff;
    }
    __syncthreads();
  }
}

// ------- mrconv2: gather+max (VALU/mem) + MFMA 256->128 linear + BN+gelu+res
__global__ __launch_bounds__(256) void mrconv2_k(const float* __restrict__ in,
                                                 const int* __restrict__ nbr,
                                                 const unsigned short* __restrict__ Whi,
                                                 const unsigned short* __restrict__ Wlo,
                                                 const float* __restrict__ bias,
                                                 const float* __restrict__ gam,
                                                 const float* __restrict__ bet,
                                                 const float* __restrict__ mean,
                                                 const float* __restrict__ var,
                                                 float* __restrict__ out) {
  __shared__ float h[32][260];
  const int tid = threadIdx.x;
  const int pt0 = blockIdx.x * 32;
  {
    const int w = tid >> 6, lane = tid & 63;
    for (int pp = 0; pp < 8; ++pp) {
      const int p = w * 8 + pp;
      const int n = pt0 + p;
      const int b = n >> 13;
      const float* frow = in + (size_t)n * CH;
      float2 f2 = *(const float2*)(frow + lane * 2);
      float mx = -FLT_MAX, my = -FLT_MAX;
      const int* nb = nbr + (size_t)n * NBRS;
      for (int j = 0; j < NBRS; ++j) {
        int idx = nb[j];
        const float* vrow = in + ((size_t)b * NT + idx) * CH;
        float2 v2 = *(const float2*)(vrow + lane * 2);
        mx = fmaxf(mx, v2.x - f2.x);
        my = fmaxf(my, v2.y - f2.y);
      }
      h[p][lane * 4 + 0] = f2.x; h[p][lane * 4 + 1] = mx;
      h[p][lane * 4 + 2] = f2.y; h[p][lane * 4 + 3] = my;
    }
  }
  __syncthreads();
  const int lane = tid & 63, w = tid >> 6;
  const int r16 = lane & 15, kg = lane >> 4;
  f32x4 acc[2][2] = {{{0.f,0.f,0.f,0.f},{0.f,0.f,0.f,0.f}},
                     {{0.f,0.f,0.f,0.f},{0.f,0.f,0.f,0.f}}};
#pragma unroll
  for (int ks = 0; ks < 8; ++ks) {
    s16x8 ah[2], al[2];
#pragma unroll
    for (int rt = 0; rt < 2; ++rt) {
      const float* hp = &h[rt * 16 + r16][(ks * 4 + kg) * 8];
#pragma unroll
      for (int j = 0; j < 8; ++j) {
        float v = hp[j];
        unsigned short hb = f2bf(v);
        float rr = v - bf2f(hb);
        ah[rt][j] = (short)hb;
        al[rt][j] = (short)f2bf(rr);
      }
    }
#pragma unroll
    for (int cbi = 0; cbi < 2; ++cbi) {
      const int o = (w * 2 + cbi) * 16 + r16;
      s16x8 bh2 = *(const s16x8*)(Whi + o * 256 + ks * 32 + kg * 8);
      s16x8 bl2 = *(const s16x8*)(Wlo + o * 256 + ks * 32 + kg * 8);
#pragma unroll
      for (int rt = 0; rt < 2; ++rt) {
        acc[rt][cbi] = __builtin_amdgcn_mfma_f32_16x16x32_bf16(ah[rt], bh2, acc[rt][cbi], 0, 0, 0);
        acc[rt][cbi] = __builtin_amdgcn_mfma_f32_16x16x32_bf16(ah[rt], bl2, acc[rt][cbi], 0, 0, 0);
        acc[rt][cbi] = __builtin_amdgcn_mfma_f32_16x16x32_bf16(al[rt], bh2, acc[rt][cbi], 0, 0, 0);
      }
    }
  }
#pragma unroll
  for (int cbi = 0; cbi < 2; ++cbi) {
    const int o = (w * 2 + cbi) * 16 + r16;
    const float sc = gam[o] / sqrtf(var[o] + 1e-5f);
    const float bs = bias[o], mo = mean[o], be = bet[o];
#pragma unroll
    for (int rt = 0; rt < 2; ++rt) {
#pragma unroll
      for (int rg = 0; rg < 4; ++rg) {
        const int row = rt * 16 + kg * 4 + rg;
        const int n = pt0 + row;
        float bn = (acc[rt][cbi][rg] + bs - mo) * sc + be;
        float gl = gelu_f(bn);
        out[(size_t)n * CH + o] = gl + h[row][2 * o];
      }
    }
  }
}

// --------- fc2: MFMA linear 128->128 + BN + residual. 16 points/block.
__global__ __launch_bounds__(256) void fc2_k(const float* __restrict__ in,
                                             const unsigned short* __restrict__ Whi,
                                             const unsigned short* __restrict__ Wlo,
                                             const float* __restrict__ bias,
                                             const float* __restrict__ gam,
                                             const float* __restrict__ bet,
                                             const float* __restrict__ mean,
                                             const float* __restrict__ var,
                                             const float* __restrict__ xres,
                                             const float* __restrict__ yres,
                                             float* __restrict__ out) {
  __shared__ unsigned short __align__(16) aHi[16][16][8];
  __shared__ unsigned short __align__(16) aLo[16][16][8];
  const int tid = threadIdx.x;
  const int pt0 = blockIdx.x * 16;
  {
    const int row = tid >> 4, ku = tid & 15;
    const float* src = in + (size_t)(pt0 + row) * CH + ku * 8;
    unsigned hw[4], lw[4];
#pragma unroll
    for (int j = 0; j < 4; ++j) {
      float v0 = src[2 * j], v1 = src[2 * j + 1];
      unsigned short h0 = f2bf(v0), h1 = f2bf(v1);
      float r0 = v0 - bf2f(h0), r1 = v1 - bf2f(h1);
      hw[j] = (unsigned)h0 | ((unsigned)h1 << 16);
      lw[j] = (unsigned)f2bf(r0) | ((unsigned)f2bf(r1) << 16);
    }
    *(uint4*)&aHi[ku][row][0] = make_uint4(hw[0], hw[1], hw[2], hw[3]);
    *(uint4*)&aLo[ku][row][0] = make_uint4(lw[0], lw[1], lw[2], lw[3]);
  }
  __syncthreads();
  const int lane = tid & 63, w = tid >> 6;
  const int r16 = lane & 15, kg = lane >> 4;
  f32x4 acc[2] = {{0.f,0.f,0.f,0.f}, {0.f,0.f,0.f,0.f}};
#pragma unroll
  for (int ks = 0; ks < 4; ++ks) {
    s16x8 ah = *(const s16x8*)&aHi[ks * 4 + kg][r16][0];
    s16x8 al = *(const s16x8*)&aLo[ks * 4 + kg][r16][0];
#pragma unroll
    for (int cb = 0; cb < 2; ++cb) {
      const int o = w * 32 + cb * 16 + r16;
      s16x8 bh2 = *(const s16x8*)(Whi + o * 128 + ks * 32 + kg * 8);
      s16x8 bl2 = *(const s16x8*)(Wlo + o * 128 + ks * 32 + kg * 8);
      acc[cb] = __builtin_amdgcn_mfma_f32_16x16x32_bf16(ah, bh2, acc[cb], 0, 0, 0);
      acc[cb] = __builtin_amdgcn_mfma_f32_16x16x32_bf16(ah, bl2, acc[cb], 0, 0, 0);
      acc[cb] = __builtin_amdgcn_mfma_f32_16x16x32_bf16(al, bh2, acc[cb], 0, 0, 0);
    }
  }
#pragma unroll
  for (int cb = 0; cb < 2; ++cb) {
    const int o = w * 32 + cb * 16 + r16;
    const float sc = gam[o] / sqrtf(var[o] + 1e-5f);
    const float bs = bias[o], mo = mean[o], be = bet[o];
#pragma unroll
    for (int rg = 0; rg < 4; ++rg) {
      const int row = kg * 4 + rg;
      const int n = pt0 + row;
      const int b = n >> 13, prow = n & 8191;
      float bn = (acc[cb][rg] + bs - mo) * sc + be;
      float res = (prow < N1) ? xres[((size_t)b * N1 + prow) * CH + o]
                              : yres[((size_t)b * N1 + prow - N1) * CH + o];
      out[(size_t)n * CH + o] = bn + res;
    }
  }
}

// --------- ffn2: MFMA fused 128->512(GELU)->128 + BN + res + mask.
__global__ __launch_bounds__(256) void ffn2_k(const float* __restrict__ u,
                                              const unsigned short* __restrict__ W1hi,
                                              const unsigned short* __restrict__ W1lo,
                                              const float* __restrict__ b1,
                                              const float* __restrict__ g1,
                                              const float* __restrict__ be1,
                                              const float* __restrict__ m1,
                                              const float* __restrict__ v1,
                                              const unsigned short* __restrict__ W2hi,
                                              const unsigned short* __restrict__ W2lo,
                                              const float* __restrict__ b2,
                                              const float* __restrict__ g2,
                                              const float* __restrict__ be2,
                                              const float* __restrict__ m2,
                                              const float* __restrict__ v2,
                                              const float* __restrict__ xmask,
                                              const float* __restrict__ ymask,
                                              float* __restrict__ outbuf) {
  __shared__ unsigned short __align__(16) aHi[16][16][8];
  __shared__ unsigned short __align__(16) aLo[16][16][8];
  __shared__ unsigned short __align__(16) hHi[64][16][8];
  __shared__ unsigned short __align__(16) hLo[64][16][8];
  const int tid = threadIdx.x;
  const int pt0 = blockIdx.x * 16;
  {
    const int row = tid >> 4, ku = tid & 15;
    const float* src = u + (size_t)(pt0 + row) * CH + ku * 8;
    unsigned hw[4], lw[4];
#pragma unroll
    for (int j = 0; j < 4; ++j) {
      float v0 = src[2 * j], v1 = src[2 * j + 1];
      unsigned short h0 = f2bf(v0), h1 = f2bf(v1);
      float r0 = v0 - bf2f(h0), r1 = v1 - bf2f(h1);
      hw[j] = (unsigned)h0 | ((unsigned)h1 << 16);
      lw[j] = (unsigned)f2bf(r0) | ((unsigned)f2bf(r1) << 16);
    }
    *(uint4*)&aHi[ku][row][0] = make_uint4(hw[0], hw[1], hw[2], hw[3]);
    *(uint4*)&aLo[ku][row][0] = make_uint4(lw[0], lw[1], lw[2], lw[3]);
  }
  __syncthreads();
  const int lane = tid & 63, w = tid >> 6;
  const int r16 = lane & 15, kg = lane >> 4;
  {
    f32x4 acc[8];
#pragma unroll
    for (int cb = 0; cb < 8; ++cb) acc[cb] = {0.f, 0.f, 0.f, 0.f};
#pragma unroll
    for (int ks = 0; ks < 4; ++ks) {
      s16x8 ah = *(const s16x8*)&aHi[ks * 4 + kg][r16][0];
      s16x8 al = *(const s16x8*)&aLo[ks * 4 + kg][r16][0];
#pragma unroll
      for (int cb = 0; cb < 8; ++cb) {
        const int o = w * 128 + cb * 16 + r16;
        s16x8 bh2 = *(const s16x8*)(W1hi + o * 128 + ks * 32 + kg * 8);
        s16x8 bl2 = *(const s16x8*)(W1lo + o * 128 + ks * 32 + kg * 8);
        acc[cb] = __builtin_amdgcn_mfma_f32_16x16x32_bf16(ah, bh2, acc[cb], 0, 0, 0);
        acc[cb] = __builtin_amdgcn_mfma_f32_16x16x32_bf16(ah, bl2, acc[cb], 0, 0, 0);
        acc[cb] = __builtin_amdgcn_mfma_f32_16x16x32_bf16(al, bh2, acc[cb], 0, 0, 0);
      }
    }
#pragma unroll
    for (int cb = 0; cb < 8; ++cb) {
      const int o = w * 128 + cb * 16 + r16;
      const float sc = g1[o] / sqrtf(v1[o] + 1e-5f);
      const float bs = b1[o], mo = m1[o], be = be1[o];
#pragma unroll
      for (int rg = 0; rg < 4; ++rg) {
        const int row = kg * 4 + rg;
        float bn = (acc[cb][rg] + bs - mo) * sc + be;
        float gl = gelu_f(bn);
        unsigned short hb = f2bf(gl);
        float rr = gl - bf2f(hb);
        hHi[o >> 3][row][o & 7] = hb;
        hLo[o >> 3][row][o & 7] = f2bf(rr);
      }
    }
  }
  __syncthreads();
  {
    f32x4 acc[2] = {{0.f,0.f,0.f,0.f}, {0.f,0.f,0.f,0.f}};
#pragma unroll
    for (int ks = 0; ks < 16; ++ks) {
      s16x8 ah = *(const s16x8*)&hHi[ks * 4 + kg][r16][0];
      s16x8 al = *(const s16x8*)&hLo[ks * 4 + kg][r16][0];
#pragma unroll
      for (int cb = 0; cb < 2; ++cb) {
        const int o = w * 32 + cb * 16 + r16;
        s16x8 bh2 = *(const s16x8*)(W2hi + o * 512 + ks * 32 + kg * 8);
        s16x8 bl2 = *(const s16x8*)(W2lo + o * 512 + ks * 32 + kg * 8);
        acc[cb] = __builtin_amdgcn_mfma_f32_16x16x32_bf16(ah, bh2, acc[cb], 0, 0, 0);
        acc[cb] = __builtin_amdgcn_mfma_f32_16x16x32_bf16(ah, bl2, acc[cb], 0, 0, 0);
        acc[cb] = __builtin_amdgcn_mfma_f32_16x16x32_bf16(al, bh2, acc[cb], 0, 0, 0);
      }
    }
#pragma unroll
    for (int cb = 0; cb < 2; ++cb) {
      const int o = w * 32 + cb * 16 + r16;
      const float sc = g2[o] / sqrtf(v2[o] + 1e-5f);
      const float bs = b2[o], mo = m2[o], be = be2[o];
#pragma unroll
      for (int rg = 0; rg < 4; ++rg) {
        const int row = kg * 4 + rg;
        const int n = pt0 + row;
        const int b = n >> 13, prow = n & 8191;
        float bn = (acc[cb][rg] + bs - mo) * sc + be;
        float gl = gelu_f(bn);
        float res = u[(size_t)n * CH + o];
        float msk; size_t oidx;
        if (prow < N1) {
          msk = xmask[(size_t)b * N1 + prow];
          oidx = ((size_t)b * N1 + prow) * CH + o;
        } else {
          msk = ymask[(size_t)b * N1 + prow - N1];
          oidx = (size_t)BB * N1 * CH + ((size_t)b * N1 + prow - N1) * CH + o;
        }
        outbuf[oidx] = (gl + res) * msk;
      }
    }
  }
}

// ---------------------------------------------------------------------------
extern "C" void kernel_launch(void* const* d_in, const int* in_sizes, int n_in,
                              void* d_out, int out_size, void* d_ws, size_t ws_size,
                              hipStream_t stream) {
  const float* x  = (const float*)d_in[0];
  const float* y  = (const float*)d_in[1];
  const float* xm = (const float*)d_in[2];
  const float* ym = (const float*)d_in[3];
  const float* mr0W = (const float*)d_in[4];
  const float* mr1W = (const float*)d_in[10];
  const float* fcW  = (const float*)d_in[16];
  const float* f1W  = (const float*)d_in[22];
  const float* f2W  = (const float*)d_in[28];

  char* ws = (char*)d_ws;
  float*          xyA   = (float*)(ws + 0);
  unsigned short* cbt   = (unsigned short*)(ws + 16777216);
  float*          xyB   = (float*)(ws + 16777216);
  float*          norms = (float*)(ws + 33554432);
  int*            cntg  = (int*)(ws + 33685504);
  unsigned*       listA = (unsigned*)(ws + 33689600);
  unsigned*       listB = (unsigned*)(ws + 33951744);
  unsigned short* fbl   = (unsigned short*)(ws + 34213888);  // 3.15 MB
  int*            nbr   = (int*)(ws + 37359616);             // 2.36 MB
  unsigned short* mr0hi = (unsigned short*)(ws + 39718912);  // 64 KB
  unsigned short* mr0lo = (unsigned short*)(ws + 39784448);
  unsigned short* mr1hi = (unsigned short*)(ws + 39849984);
  unsigned short* mr1lo = (unsigned short*)(ws + 39915520);
  unsigned short* fcWhi = (unsigned short*)(ws + 39981056);  // 32 KB
  unsigned short* fcWlo = (unsigned short*)(ws + 40013824);
  unsigned short* f1hi  = (unsigned short*)(ws + 40046592);  // 128 KB
  unsigned short* f1lo  = (unsigned short*)(ws + 40177664);
  unsigned short* f2hi  = (unsigned short*)(ws + 40308736);
  unsigned short* f2lo  = (unsigned short*)(ws + 40439808);  // end 40.57 MB

  hipMemsetAsync(cntg, 0, 8, stream);

  wsplit_k<<<128, 256, 0, stream>>>(mr0W, mr0hi, mr0lo, 128 * 256);
  wsplit_k<<<128, 256, 0, stream>>>(mr1W, mr1hi, mr1lo, 128 * 256);
  wsplit_k<<<64, 256, 0, stream>>>(fcW, fcWhi, fcWlo, 128 * 128);
  wsplit_k<<<256, 256, 0, stream>>>(f1W, f1hi, f1lo, 512 * 128);
  wsplit_k<<<256, 256, 0, stream>>>(f2W, f2hi, f2lo, 128 * 512);

  norms_concat_k<<<8192, 256, 0, stream>>>(x, y, xyA, norms);
  cbt_k<<<2048, 256, 0, stream>>>(xyA, cbt);
  knn9_k<<<dim3(32, 16), 256, 0, stream>>>(cbt, norms, nbr, cntg, listA, listB, fbl);
  rerank_sl_k<<<256, 256, 0, stream>>>(xyA, norms, fbl, listA, cntg, nbr);
  rerank_fs_k<<<256, 256, 0, stream>>>(xyA, norms, listB, cntg, nbr);

  mrconv2_k<<<1024, 256, 0, stream>>>(xyA, nbr, mr0hi, mr0lo,
      (const float*)d_in[5], (const float*)d_in[6], (const float*)d_in[7],
      (const float*)d_in[8], (const float*)d_in[9], xyB);
  mrconv2_k<<<1024, 256, 0, stream>>>(xyB, nbr, mr1hi, mr1lo,
      (const float*)d_in[11], (const float*)d_in[12], (const float*)d_in[13],
      (const float*)d_in[14], (const float*)d_in[15], xyA);

  fc2_k<<<2048, 256, 0, stream>>>(xyA, fcWhi, fcWlo,
      (const float*)d_in[17], (const float*)d_in[18], (const float*)d_in[19],
      (const float*)d_in[20], (const float*)d_in[21], x, y, xyB);

  ffn2_k<<<2048, 256, 0, stream>>>(xyB,
      f1hi, f1lo, (const float*)d_in[23], (const float*)d_in[24], (const float*)d_in[25],
      (const float*)d_in[26], (const float*)d_in[27],
      f2hi, f2lo, (const float*)d_in[29], (const float*)d_in[30], (const float*)d_in[31],
      (const float*)d_in[32], (const float*)d_in[33],
      xm, ym, (float*)d_out);
}

// Round 17
// 576.077 us; speedup vs baseline: 1.0549x; 1.0549x over previous
//
#include <hip/hip_runtime.h>
#include <hip/hip_bf16.h>
#include <float.h>
#include <math.h>

#define BB 4
#define N1 4096
#define NT 8192
#define CH 128
#define NBRS 18
#define ZSEL 2.35f
#define LCAP 40
#define EQ 4096.0f
#define GQGAP 6
#define GQCOV 3

typedef __attribute__((ext_vector_type(8))) short s16x8;
typedef __attribute__((ext_vector_type(16))) float f32x16;
typedef __attribute__((ext_vector_type(4))) float f32x4;

__device__ inline unsigned short f2bf(float v) {
  unsigned u = __float_as_uint(v);
  unsigned r = (u + 0x7FFFu + ((u >> 16) & 1u)) >> 16;
  return (unsigned short)r;
}
__device__ inline float bf2f(unsigned short h) {
  return __uint_as_float((unsigned)h << 16);
}
__device__ inline unsigned mapf(float f) {
  unsigned u = __float_as_uint(f);
  return (u & 0x80000000u) ? ~u : (u | 0x80000000u);
}
__device__ inline float gelu_f(float x) {
  return 0.5f * x * (1.0f + erff(x * 0.70710678118654752f));
}

// --------------------------------------------- split f32 weights -> hi/lo bf16
__global__ __launch_bounds__(256) void wsplit_k(const float* __restrict__ w,
                                                unsigned short* __restrict__ hi,
                                                unsigned short* __restrict__ lo,
                                                int n) {
  int t = blockIdx.x * 256 + threadIdx.x;
  if (t < n) {
    float v = w[t];
    unsigned short h = f2bf(v);
    float r = v - bf2f(h);
    hi[t] = h; lo[t] = f2bf(r);
  }
}

// ------------------------------------------------- concat x,y + squared norms
__global__ __launch_bounds__(256) void norms_concat_k(const float* __restrict__ x,
                                                      const float* __restrict__ y,
                                                      float* __restrict__ xy,
                                                      float* __restrict__ norms) {
  int w = (blockIdx.x * 256 + threadIdx.x) >> 6;
  int lane = threadIdx.x & 63;
  int b = w >> 13, row = w & 8191;
  const float* src = (row < N1) ? (x + ((size_t)b * N1 + row) * CH)
                                : (y + ((size_t)b * N1 + (row - N1)) * CH);
  float2 v = *(const float2*)(src + lane * 2);
  *(float2*)(xy + (size_t)w * CH + lane * 2) = v;
  float s = v.x * v.x + v.y * v.y;
  for (int off = 32; off > 0; off >>= 1) s += __shfl_down(s, off);
  if (lane == 0) norms[w] = s;
}

// ---------------------------------------- build split-bf16 k-major candidate buf
__global__ __launch_bounds__(256) void cbt_k(const float* __restrict__ xy,
                                             unsigned short* __restrict__ cbt) {
  int t = blockIdx.x * 256 + threadIdx.x;
  int u = t >> 15, p = t & 32767;
  const float* src = xy + (size_t)p * CH + u * 8;
  unsigned hw[4], lw[4];
#pragma unroll
  for (int j = 0; j < 4; ++j) {
    float v0 = src[2 * j], v1 = src[2 * j + 1];
    unsigned short h0 = f2bf(v0), h1 = f2bf(v1);
    float r0 = v0 - bf2f(h0);
    float r1 = v1 - bf2f(h1);
    unsigned short l0 = f2bf(r0), l1 = f2bf(r1);
    hw[j] = (unsigned)h0 | ((unsigned)h1 << 16);
    lw[j] = (unsigned)l0 | ((unsigned)l1 << 16);
  }
  *(uint4*)&cbt[((size_t)u * 32768 + p) * 8] = make_uint4(hw[0], hw[1], hw[2], hw[3]);
  *(uint4*)&cbt[((size_t)(u + 16) * 32768 + p) * 8] = make_uint4(lw[0], lw[1], lw[2], lw[3]);
}

// ------------- MFMA knn: threshold-collect to LDS + in-kernel certify/select
__global__ __launch_bounds__(256) void knn4_k(const unsigned short* __restrict__ cbt,
                                              const float* __restrict__ norms,
                                              int* __restrict__ nbr,
                                              int* __restrict__ cntg,
                                              unsigned* __restrict__ listA,
                                              unsigned* __restrict__ listB,
                                              unsigned short* __restrict__ fbl) {
  __shared__ unsigned short __align__(16) cst[2][32][32][8];
  __shared__ float cn_s[2][32];
  __shared__ unsigned lst[128][2][LCAP];
  __shared__ unsigned short lcnt[128][2];
  const int tid = threadIdx.x;
  const int qblk = blockIdx.x, z = blockIdx.y;
  const int b = z >> 2, combo = z & 3;
  const int qoff = (combo <= 1) ? 0 : N1;
  const int coff = (combo == 0 || combo == 3) ? 0 : N1;
  const int w = tid >> 6;
  const int cl = tid & 31;
  const int h = (tid >> 5) & 1;
  const int h4 = 4 * h;
  const int ql = w * 32 + cl;
  const int q = qblk * 128 + ql;
  const size_t qp = (size_t)b * NT + qoff + q;
  const size_t cb0 = (size_t)b * NT + coff;

  const s16x8* cv = (const s16x8*)cbt;
  s16x8 bh[8], bl[8];
#pragma unroll
  for (int s = 0; s < 8; ++s) {
    bh[s] = cv[(size_t)(2 * s + h) * 32768 + qp];
    bl[s] = cv[(size_t)(16 + 2 * s + h) * 32768 + qp];
  }

  const float nq = norms[qp];
  const float Tc = 128.f - ZSEL * sqrtf(256.f + 4.f * nq);
  int cnt = 0;

  const int su = tid >> 5, sc = tid & 31;
  const char* p0 = (const char*)&cbt[((size_t)(su) * 32768 + cb0 + sc) * 8];
  const char* p1 = (const char*)&cbt[((size_t)(8 + su) * 32768 + cb0 + sc) * 8];
  const char* p2 = (const char*)&cbt[((size_t)(16 + su) * 32768 + cb0 + sc) * 8];
  const char* p3 = (const char*)&cbt[((size_t)(24 + su) * 32768 + cb0 + sc) * 8];
  const float* pn = norms + cb0 + tid;

  uint4 st[4]; float cnreg = 0.f;
  st[0] = *(const uint4*)p0; p0 += 512;
  st[1] = *(const uint4*)p1; p1 += 512;
  st[2] = *(const uint4*)p2; p2 += 512;
  st[3] = *(const uint4*)p3; p3 += 512;
  if (tid < 32) { cnreg = *pn; pn += 32; }
  *(uint4*)&cst[0][su][sc][0] = st[0];
  *(uint4*)&cst[0][8 + su][sc][0] = st[1];
  *(uint4*)&cst[0][16 + su][sc][0] = st[2];
  *(uint4*)&cst[0][24 + su][sc][0] = st[3];
  if (tid < 32) cn_s[0][tid] = cnreg;
  __syncthreads();

  int buf = 0;
  for (int t = 0; t < 128; ++t) {
    if (t < 127) {
      st[0] = *(const uint4*)p0; p0 += 512;
      st[1] = *(const uint4*)p1; p1 += 512;
      st[2] = *(const uint4*)p2; p2 += 512;
      st[3] = *(const uint4*)p3; p3 += 512;
      if (tid < 32) { cnreg = *pn; pn += 32; }
    }
    f32x16 acc = {0.f,0.f,0.f,0.f,0.f,0.f,0.f,0.f,0.f,0.f,0.f,0.f,0.f,0.f,0.f,0.f};
#pragma unroll
    for (int s = 0; s < 8; ++s) {
      s16x8 a0 = *(const s16x8*)&cst[buf][2 * s + h][cl][0];
      s16x8 a1 = *(const s16x8*)&cst[buf][16 + 2 * s + h][cl][0];
      acc = __builtin_amdgcn_mfma_f32_32x32x16_bf16(a0, bh[s], acc, 0, 0, 0);
      acc = __builtin_amdgcn_mfma_f32_32x32x16_bf16(a0, bl[s], acc, 0, 0, 0);
      acc = __builtin_amdgcn_mfma_f32_32x32x16_bf16(a1, bh[s], acc, 0, 0, 0);
    }
    float4 c0 = *(const float4*)&cn_s[buf][h4];
    float4 c1 = *(const float4*)&cn_s[buf][8 + h4];
    float4 c2 = *(const float4*)&cn_s[buf][16 + h4];
    float4 c3 = *(const float4*)&cn_s[buf][24 + h4];
    const float cw[16] = {c0.x, c0.y, c0.z, c0.w, c1.x, c1.y, c1.z, c1.w,
                          c2.x, c2.y, c2.z, c2.w, c3.x, c3.y, c3.z, c3.w};
    const int ib = t * 32 + h4;
#pragma unroll
    for (int g = 0; g < 4; ++g) {
#pragma unroll
      for (int rr = 0; rr < 4; ++rr) {
        const int r = g * 4 + rr;
        float s = fmaf(-2.0f, acc[r], cw[r]);
        if (s <= Tc) {
          int e = (int)((Tc - s) * EQ);
          e = e > 0xFFFFF ? 0xFFFFF : e;
          unsigned key = ((unsigned)e << 12) | (unsigned)(4095 - (ib + g * 8 + rr));
          if (cnt < LCAP) lst[ql][h][cnt] = key;
          ++cnt;
        }
      }
    }
    if (t < 127) {
      *(uint4*)&cst[buf ^ 1][su][sc][0] = st[0];
      *(uint4*)&cst[buf ^ 1][8 + su][sc][0] = st[1];
      *(uint4*)&cst[buf ^ 1][16 + su][sc][0] = st[2];
      *(uint4*)&cst[buf ^ 1][24 + su][sc][0] = st[3];
      if (tid < 32) cn_s[buf ^ 1][tid] = cnreg;
    }
    __syncthreads();
    buf ^= 1;
  }
  lcnt[ql][h] = (unsigned short)cnt;
  __syncthreads();

  if (tid < 128) {
    const int mq = tid;
    const int gq = z * 4096 + qblk * 128 + mq;
    const int c0 = lcnt[mq][0], c1 = lcnt[mq][1];
    const bool over = (c0 > LCAP) || (c1 > LCAP);
    const int n0 = c0 > LCAP ? LCAP : c0;
    const int n1 = c1 > LCAP ? LCAP : c1;
    const int m = n0 + n1;
    unsigned top[10];
#pragma unroll
    for (int j = 0; j < 10; ++j) top[j] = 0u;
    for (int li = 0; li < 2; ++li) {
      const int n = li ? n1 : n0;
      for (int i = 0; i < n; ++i) {
        unsigned key = lst[mq][li][i];
        if (key > top[9]) {
#pragma unroll
          for (int j = 0; j < 10; ++j) {
            bool sw = key > top[j];
            unsigned tv = top[j];
            top[j] = sw ? key : tv;
            key = sw ? tv : key;
          }
        }
      }
    }
    const unsigned e8 = top[8] >> 12, e9 = top[9] >> 12;
    const bool cov = !over && (m >= 9) && (e8 >= GQCOV);
    const bool ok = cov && (m == 9 || (e8 - e9) >= GQGAP);
    const int qg = qblk * 128 + mq;
    const int row = (combo <= 1) ? qg : (N1 + qg);
    const int slot = (combo == 0 || combo == 2) ? 0 : 9;
    const int ioff = (combo == 1 || combo == 2) ? N1 : 0;
    int* dst = nbr + ((size_t)b * NT + row) * NBRS + slot;
    if (ok) {
#pragma unroll
      for (int s = 0; s < 9; ++s)
        dst[s] = (int)(4095u - (top[s] & 0xFFFu)) + ioff;
    } else if (!cov || m > 64) {
      int idx = atomicAdd(&cntg[1], 1);
      listB[idx] = (unsigned)gq;
    } else {
      int idx = atomicAdd(&cntg[0], 1);
      listA[idx] = ((unsigned)m << 16) | (unsigned)gq;
      unsigned short* fp = fbl + (size_t)gq * 64;
      int p = 0;
      for (int i = 0; i < n0; ++i) fp[p++] = (unsigned short)(4095u - (lst[mq][0][i] & 0xFFFu));
      for (int i = 0; i < n1; ++i) fp[p++] = (unsigned short)(4095u - (lst[mq][1][i] & 0xFFFu));
    }
  }
}

// ------- rerank_sl: grid-stride over compacted shortlist queries (wave each)
__global__ __launch_bounds__(256) void rerank_sl_k(const float* __restrict__ xy,
                                                   const float* __restrict__ norms,
                                                   const unsigned short* __restrict__ fbl,
                                                   const unsigned* __restrict__ listA,
                                                   const int* __restrict__ cntg,
                                                   int* __restrict__ nbr) {
  const int lane = threadIdx.x & 63;
  const int wv = threadIdx.x >> 6;
  const int nA = cntg[0];
  for (int i = blockIdx.x * 4 + wv; i < nA; i += gridDim.x * 4) {
    const unsigned ent = listA[i];
    const int gq = (int)(ent & 0xffffu);
    const int m = (int)(ent >> 16);
    const int z = gq >> 12, q = gq & 4095;
    const int b = z >> 2, combo = z & 3;
    const int qoff = (combo <= 1) ? 0 : N1;
    const int coff = (combo == 0 || combo == 3) ? 0 : N1;
    const size_t cq = (size_t)b * NT + coff;
    const int row = (combo <= 1) ? q : (N1 + q);
    const int slot = (combo == 0 || combo == 2) ? 0 : 9;
    const int ioff = (combo == 1 || combo == 2) ? N1 : 0;
    int* dst = nbr + ((size_t)b * NT + row) * NBRS + slot;
    const float* qrow = xy + ((size_t)b * NT + qoff + q) * CH;

    int ci = 0; float de = FLT_MAX;
    if (lane < m) {
      ci = (int)fbl[(size_t)gq * 64 + lane];
      const float* crow = xy + (cq + ci) * CH;
      const float cnv = norms[cq + ci];
      float a0 = 0.f, a1 = 0.f, a2 = 0.f, a3 = 0.f;
#pragma unroll
      for (int k = 0; k < 32; ++k) {
        float4 qv = *(const float4*)(qrow + k * 4);
        float4 cv2 = *(const float4*)(crow + k * 4);
        a0 = fmaf(qv.x, cv2.x, a0); a1 = fmaf(qv.y, cv2.y, a1);
        a2 = fmaf(qv.z, cv2.z, a2); a3 = fmaf(qv.w, cv2.w, a3);
      }
      de = cnv - 2.0f * ((a0 + a1) + (a2 + a3));
    }
    unsigned long long key = ((unsigned long long)mapf(de) << 32) | (unsigned)ci;
    if (lane >= m) key = ~0ull;
    int xr = 0;
#pragma unroll 1
    for (int k = 0; k < m; ++k) {
      unsigned long long kk = __shfl(key, k);
      xr += (kk < key) ? 1 : 0;
    }
    if (lane < m && xr < 9) dst[xr] = ci + ioff;
  }
}

// ------- rerank_fs: grid-stride over full-scan queries (one BLOCK each)
__global__ __launch_bounds__(256) void rerank_fs_k(const float* __restrict__ xy,
                                                   const float* __restrict__ norms,
                                                   const unsigned* __restrict__ listB,
                                                   const int* __restrict__ cntg,
                                                   int* __restrict__ nbr) {
  __shared__ unsigned long long ms[4][576];
  __shared__ unsigned long long wk[36];
  const int tid = threadIdx.x;
  const int lane = tid & 63, wv = tid >> 6;
  const int nB = cntg[1];
  for (int i = blockIdx.x; i < nB; i += gridDim.x) {
    const int gq = (int)listB[i];
    const int z = gq >> 12, q = gq & 4095;
    const int b = z >> 2, combo = z & 3;
    const int qoff = (combo <= 1) ? 0 : N1;
    const int coff = (combo == 0 || combo == 3) ? 0 : N1;
    const size_t cq = (size_t)b * NT + coff;
    const int row = (combo <= 1) ? q : (N1 + q);
    const int slot = (combo == 0 || combo == 2) ? 0 : 9;
    const int ioff = (combo == 1 || combo == 2) ? N1 : 0;
    int* dst = nbr + ((size_t)b * NT + row) * NBRS + slot;
    const float* qrow = xy + ((size_t)b * NT + qoff + q) * CH;

    unsigned long long bl9[9];
#pragma unroll
    for (int j = 0; j < 9; ++j) bl9[j] = ~0ull;
    for (int it = 0; it < 16; ++it) {
      const int cc = (it * 4 + wv) * 64 + lane;
      const float* crow = xy + (cq + cc) * CH;
      float a0 = 0.f, a1 = 0.f, a2 = 0.f, a3 = 0.f;
#pragma unroll
      for (int k = 0; k < 32; ++k) {
        float4 qv = *(const float4*)(qrow + k * 4);
        float4 cv2 = *(const float4*)(crow + k * 4);
        a0 = fmaf(qv.x, cv2.x, a0); a1 = fmaf(qv.y, cv2.y, a1);
        a2 = fmaf(qv.z, cv2.z, a2); a3 = fmaf(qv.w, cv2.w, a3);
      }
      float d2v = norms[cq + cc] - 2.0f * ((a0 + a1) + (a2 + a3));
      unsigned long long key = ((unsigned long long)mapf(d2v) << 32) | (unsigned)cc;
      if (key < bl9[8]) {
#pragma unroll
        for (int jj = 0; jj < 9; ++jj) {
          bool sw = key < bl9[jj];
          unsigned long long tv = bl9[jj];
          bl9[jj] = sw ? key : tv;
          key = sw ? tv : key;
        }
      }
    }
#pragma unroll
    for (int s = 0; s < 9; ++s) ms[wv][lane * 9 + s] = bl9[s];
    int ptr = 0;
    for (int s = 0; s < 9; ++s) {
      unsigned long long hd = ms[wv][lane * 9 + ptr];
      unsigned long long mn = hd;
#pragma unroll
      for (int off = 1; off < 64; off <<= 1) {
        unsigned long long ot = __shfl_xor(mn, off);
        mn = (ot < mn) ? ot : mn;
      }
      unsigned long long wm = __ballot(hd == mn);
      int wl = __ffsll(wm) - 1;
      if (lane == wl) ptr++;
      if (lane == 0) wk[wv * 9 + s] = mn;
    }
    __syncthreads();
    if (wv == 0) {
      unsigned long long key = (lane < 36) ? wk[lane] : ~0ull;
      int xr = 0;
#pragma unroll 1
      for (int k = 0; k < 36; ++k) {
        unsigned long long kk = __shfl(key, k);
        xr += (kk < key) ? 1 : 0;
      }
      if (lane < 36 && xr < 9) dst[xr] = (int)(unsigned)(key & 0xffffffffull) + ioff;
    }
    __syncthreads();
  }
}

// ------- mrconv2: gather+max (VALU/mem) + MFMA 256->128 linear + BN+gelu+res
__global__ __launch_bounds__(256) void mrconv2_k(const float* __restrict__ in,
                                                 const int* __restrict__ nbr,
                                                 const unsigned short* __restrict__ Whi,
                                                 const unsigned short* __restrict__ Wlo,
                                                 const float* __restrict__ bias,
                                                 const float* __restrict__ gam,
                                                 const float* __restrict__ bet,
                                                 const float* __restrict__ mean,
                                                 const float* __restrict__ var,
                                                 float* __restrict__ out) {
  __shared__ float h[32][260];
  const int tid = threadIdx.x;
  const int pt0 = blockIdx.x * 32;
  {
    const int w = tid >> 6, lane = tid & 63;
    for (int pp = 0; pp < 8; ++pp) {
      const int p = w * 8 + pp;
      const int n = pt0 + p;
      const int b = n >> 13;
      const float* frow = in + (size_t)n * CH;
      float2 f2 = *(const float2*)(frow + lane * 2);
      float mx = -FLT_MAX, my = -FLT_MAX;
      const int* nb = nbr + (size_t)n * NBRS;
      for (int j = 0; j < NBRS; ++j) {
        int idx = nb[j];
        const float* vrow = in + ((size_t)b * NT + idx) * CH;
        float2 v2 = *(const float2*)(vrow + lane * 2);
        mx = fmaxf(mx, v2.x - f2.x);
        my = fmaxf(my, v2.y - f2.y);
      }
      h[p][lane * 4 + 0] = f2.x; h[p][lane * 4 + 1] = mx;
      h[p][lane * 4 + 2] = f2.y; h[p][lane * 4 + 3] = my;
    }
  }
  __syncthreads();
  const int lane = tid & 63, w = tid >> 6;
  const int r16 = lane & 15, kg = lane >> 4;
  f32x4 acc[2][2] = {{{0.f,0.f,0.f,0.f},{0.f,0.f,0.f,0.f}},
                     {{0.f,0.f,0.f,0.f},{0.f,0.f,0.f,0.f}}};
#pragma unroll
  for (int ks = 0; ks < 8; ++ks) {
    s16x8 ah[2], al[2];
#pragma unroll
    for (int rt = 0; rt < 2; ++rt) {
      const float* hp = &h[rt * 16 + r16][(ks * 4 + kg) * 8];
#pragma unroll
      for (int j = 0; j < 8; ++j) {
        float v = hp[j];
        unsigned short hb = f2bf(v);
        float rr = v - bf2f(hb);
        ah[rt][j] = (short)hb;
        al[rt][j] = (short)f2bf(rr);
      }
    }
#pragma unroll
    for (int cbi = 0; cbi < 2; ++cbi) {
      const int o = (w * 2 + cbi) * 16 + r16;
      s16x8 bh2 = *(const s16x8*)(Whi + o * 256 + ks * 32 + kg * 8);
      s16x8 bl2 = *(const s16x8*)(Wlo + o * 256 + ks * 32 + kg * 8);
#pragma unroll
      for (int rt = 0; rt < 2; ++rt) {
        acc[rt][cbi] = __builtin_amdgcn_mfma_f32_16x16x32_bf16(ah[rt], bh2, acc[rt][cbi], 0, 0, 0);
        acc[rt][cbi] = __builtin_amdgcn_mfma_f32_16x16x32_bf16(ah[rt], bl2, acc[rt][cbi], 0, 0, 0);
        acc[rt][cbi] = __builtin_amdgcn_mfma_f32_16x16x32_bf16(al[rt], bh2, acc[rt][cbi], 0, 0, 0);
      }
    }
  }
#pragma unroll
  for (int cbi = 0; cbi < 2; ++cbi) {
    const int o = (w * 2 + cbi) * 16 + r16;
    const float sc = gam[o] / sqrtf(var[o] + 1e-5f);
    const float bs = bias[o], mo = mean[o], be = bet[o];
#pragma unroll
    for (int rt = 0; rt < 2; ++rt) {
#pragma unroll
      for (int rg = 0; rg < 4; ++rg) {
        const int row = rt * 16 + kg * 4 + rg;
        const int n = pt0 + row;
        float bn = (acc[rt][cbi][rg] + bs - mo) * sc + be;
        float gl = gelu_f(bn);
        out[(size_t)n * CH + o] = gl + h[row][2 * o];
      }
    }
  }
}

// --------- fc2: MFMA linear 128->128 + BN + residual. 16 points/block.
__global__ __launch_bounds__(256) void fc2_k(const float* __restrict__ in,
                                             const unsigned short* __restrict__ Whi,
                                             const unsigned short* __restrict__ Wlo,
                                             const float* __restrict__ bias,
                                             const float* __restrict__ gam,
                                             const float* __restrict__ bet,
                                             const float* __restrict__ mean,
                                             const float* __restrict__ var,
                                             const float* __restrict__ xres,
                                             const float* __restrict__ yres,
                                             float* __restrict__ out) {
  __shared__ unsigned short __align__(16) aHi[16][16][8];
  __shared__ unsigned short __align__(16) aLo[16][16][8];
  const int tid = threadIdx.x;
  const int pt0 = blockIdx.x * 16;
  {
    const int row = tid >> 4, ku = tid & 15;
    const float* src = in + (size_t)(pt0 + row) * CH + ku * 8;
    unsigned hw[4], lw[4];
#pragma unroll
    for (int j = 0; j < 4; ++j) {
      float v0 = src[2 * j], v1 = src[2 * j + 1];
      unsigned short h0 = f2bf(v0), h1 = f2bf(v1);
      float r0 = v0 - bf2f(h0), r1 = v1 - bf2f(h1);
      hw[j] = (unsigned)h0 | ((unsigned)h1 << 16);
      lw[j] = (unsigned)f2bf(r0) | ((unsigned)f2bf(r1) << 16);
    }
    *(uint4*)&aHi[ku][row][0] = make_uint4(hw[0], hw[1], hw[2], hw[3]);
    *(uint4*)&aLo[ku][row][0] = make_uint4(lw[0], lw[1], lw[2], lw[3]);
  }
  __syncthreads();
  const int lane = tid & 63, w = tid >> 6;
  const int r16 = lane & 15, kg = lane >> 4;
  f32x4 acc[2] = {{0.f,0.f,0.f,0.f}, {0.f,0.f,0.f,0.f}};
#pragma unroll
  for (int ks = 0; ks < 4; ++ks) {
    s16x8 ah = *(const s16x8*)&aHi[ks * 4 + kg][r16][0];
    s16x8 al = *(const s16x8*)&aLo[ks * 4 + kg][r16][0];
#pragma unroll
    for (int cb = 0; cb < 2; ++cb) {
      const int o = w * 32 + cb * 16 + r16;
      s16x8 bh2 = *(const s16x8*)(Whi + o * 128 + ks * 32 + kg * 8);
      s16x8 bl2 = *(const s16x8*)(Wlo + o * 128 + ks * 32 + kg * 8);
      acc[cb] = __builtin_amdgcn_mfma_f32_16x16x32_bf16(ah, bh2, acc[cb], 0, 0, 0);
      acc[cb] = __builtin_amdgcn_mfma_f32_16x16x32_bf16(ah, bl2, acc[cb], 0, 0, 0);
      acc[cb] = __builtin_amdgcn_mfma_f32_16x16x32_bf16(al, bh2, acc[cb], 0, 0, 0);
    }
  }
#pragma unroll
  for (int cb = 0; cb < 2; ++cb) {
    const int o = w * 32 + cb * 16 + r16;
    const float sc = gam[o] / sqrtf(var[o] + 1e-5f);
    const float bs = bias[o], mo = mean[o], be = bet[o];
#pragma unroll
    for (int rg = 0; rg < 4; ++rg) {
      const int row = kg * 4 + rg;
      const int n = pt0 + row;
      const int b = n >> 13, prow = n & 8191;
      float bn = (acc[cb][rg] + bs - mo) * sc + be;
      float res = (prow < N1) ? xres[((size_t)b * N1 + prow) * CH + o]
                              : yres[((size_t)b * N1 + prow - N1) * CH + o];
      out[(size_t)n * CH + o] = bn + res;
    }
  }
}

// --------- ffn2: MFMA fused 128->512(GELU)->128 + BN + res + mask.
__global__ __launch_bounds__(256) void ffn2_k(const float* __restrict__ u,
                                              const unsigned short* __restrict__ W1hi,
                                              const unsigned short* __restrict__ W1lo,
                                              const float* __restrict__ b1,
                                              const float* __restrict__ g1,
                                              const float* __restrict__ be1,
                                              const float* __restrict__ m1,
                                              const float* __restrict__ v1,
                                              const unsigned short* __restrict__ W2hi,
                                              const unsigned short* __restrict__ W2lo,
                                              const float* __restrict__ b2,
                                              const float* __restrict__ g2,
                                              const float* __restrict__ be2,
                                              const float* __restrict__ m2,
                                              const float* __restrict__ v2,
                                              const float* __restrict__ xmask,
                                              const float* __restrict__ ymask,
                                              float* __restrict__ outbuf) {
  __shared__ unsigned short __align__(16) aHi[16][16][8];
  __shared__ unsigned short __align__(16) aLo[16][16][8];
  __shared__ unsigned short __align__(16) hHi[64][16][8];
  __shared__ unsigned short __align__(16) hLo[64][16][8];
  const int tid = threadIdx.x;
  const int pt0 = blockIdx.x * 16;
  {
    const int row = tid >> 4, ku = tid & 15;
    const float* src = u + (size_t)(pt0 + row) * CH + ku * 8;
    unsigned hw[4], lw[4];
#pragma unroll
    for (int j = 0; j < 4; ++j) {
      float v0 = src[2 * j], v1 = src[2 * j + 1];
      unsigned short h0 = f2bf(v0), h1 = f2bf(v1);
      float r0 = v0 - bf2f(h0), r1 = v1 - bf2f(h1);
      hw[j] = (unsigned)h0 | ((unsigned)h1 << 16);
      lw[j] = (unsigned)f2bf(r0) | ((unsigned)f2bf(r1) << 16);
    }
    *(uint4*)&aHi[ku][row][0] = make_uint4(hw[0], hw[1], hw[2], hw[3]);
    *(uint4*)&aLo[ku][row][0] = make_uint4(lw[0], lw[1], lw[2], lw[3]);
  }
  __syncthreads();
  const int lane = tid & 63, w = tid >> 6;
  const int r16 = lane & 15, kg = lane >> 4;
  {
    f32x4 acc[8];
#pragma unroll
    for (int cb = 0; cb < 8; ++cb) acc[cb] = {0.f, 0.f, 0.f, 0.f};
#pragma unroll
    for (int ks = 0; ks < 4; ++ks) {
      s16x8 ah = *(const s16x8*)&aHi[ks * 4 + kg][r16][0];
      s16x8 al = *(const s16x8*)&aLo[ks * 4 + kg][r16][0];
#pragma unroll
      for (int cb = 0; cb < 8; ++cb) {
        const int o = w * 128 + cb * 16 + r16;
        s16x8 bh2 = *(const s16x8*)(W1hi + o * 128 + ks * 32 + kg * 8);
        s16x8 bl2 = *(const s16x8*)(W1lo + o * 128 + ks * 32 + kg * 8);
        acc[cb] = __builtin_amdgcn_mfma_f32_16x16x32_bf16(ah, bh2, acc[cb], 0, 0, 0);
        acc[cb] = __builtin_amdgcn_mfma_f32_16x16x32_bf16(ah, bl2, acc[cb], 0, 0, 0);
        acc[cb] = __builtin_amdgcn_mfma_f32_16x16x32_bf16(al, bh2, acc[cb], 0, 0, 0);
      }
    }
#pragma unroll
    for (int cb = 0; cb < 8; ++cb) {
      const int o = w * 128 + cb * 16 + r16;
      const float sc = g1[o] / sqrtf(v1[o] + 1e-5f);
      const float bs = b1[o], mo = m1[o], be = be1[o];
#pragma unroll
      for (int rg = 0; rg < 4; ++rg) {
        const int row = kg * 4 + rg;
        float bn = (acc[cb][rg] + bs - mo) * sc + be;
        float gl = gelu_f(bn);
        unsigned short hb = f2bf(gl);
        float rr = gl - bf2f(hb);
        hHi[o >> 3][row][o & 7] = hb;
        hLo[o >> 3][row][o & 7] = f2bf(rr);
      }
    }
  }
  __syncthreads();
  {
    f32x4 acc[2] = {{0.f,0.f,0.f,0.f}, {0.f,0.f,0.f,0.f}};
#pragma unroll
    for (int ks = 0; ks < 16; ++ks) {
      s16x8 ah = *(const s16x8*)&hHi[ks * 4 + kg][r16][0];
      s16x8 al = *(const s16x8*)&hLo[ks * 4 + kg][r16][0];
#pragma unroll
      for (int cb = 0; cb < 2; ++cb) {
        const int o = w * 32 + cb * 16 + r16;
        s16x8 bh2 = *(const s16x8*)(W2hi + o * 512 + ks * 32 + kg * 8);
        s16x8 bl2 = *(const s16x8*)(W2lo + o * 512 + ks * 32 + kg * 8);
        acc[cb] = __builtin_amdgcn_mfma_f32_16x16x32_bf16(ah, bh2, acc[cb], 0, 0, 0);
        acc[cb] = __builtin_amdgcn_mfma_f32_16x16x32_bf16(ah, bl2, acc[cb], 0, 0, 0);
        acc[cb] = __builtin_amdgcn_mfma_f32_16x16x32_bf16(al, bh2, acc[cb], 0, 0, 0);
      }
    }
#pragma unroll
    for (int cb = 0; cb < 2; ++cb) {
      const int o = w * 32 + cb * 16 + r16;
      const float sc = g2[o] / sqrtf(v2[o] + 1e-5f);
      const float bs = b2[o], mo = m2[o], be = be2[o];
#pragma unroll
      for (int rg = 0; rg < 4; ++rg) {
        const int row = kg * 4 + rg;
        const int n = pt0 + row;
        const int b = n >> 13, prow = n & 8191;
        float bn = (acc[cb][rg] + bs - mo) * sc + be;
        float gl = gelu_f(bn);
        float res = u[(size_t)n * CH + o];
        float msk; size_t oidx;
        if (prow < N1) {
          msk = xmask[(size_t)b * N1 + prow];
          oidx = ((size_t)b * N1 + prow) * CH + o;
        } else {
          msk = ymask[(size_t)b * N1 + prow - N1];
          oidx = (size_t)BB * N1 * CH + ((size_t)b * N1 + prow - N1) * CH + o;
        }
        outbuf[oidx] = (gl + res) * msk;
      }
    }
  }
}

// ---------------------------------------------------------------------------
extern "C" void kernel_launch(void* const* d_in, const int* in_sizes, int n_in,
                              void* d_out, int out_size, void* d_ws, size_t ws_size,
                              hipStream_t stream) {
  const float* x  = (const float*)d_in[0];
  const float* y  = (const float*)d_in[1];
  const float* xm = (const float*)d_in[2];
  const float* ym = (const float*)d_in[3];
  const float* mr0W = (const float*)d_in[4];
  const float* mr1W = (const float*)d_in[10];
  const float* fcW  = (const float*)d_in[16];
  const float* f1W  = (const float*)d_in[22];
  const float* f2W  = (const float*)d_in[28];

  char* ws = (char*)d_ws;
  float*          xyA   = (float*)(ws + 0);
  unsigned short* cbt   = (unsigned short*)(ws + 16777216);
  float*          xyB   = (float*)(ws + 16777216);
  float*          norms = (float*)(ws + 33554432);
  int*            cntg  = (int*)(ws + 33685504);
  unsigned*       listA = (unsigned*)(ws + 33689600);
  unsigned*       listB = (unsigned*)(ws + 33951744);
  unsigned short* fbl   = (unsigned short*)(ws + 34213888);  // 8.39 MB
  int*            nbr   = (int*)(ws + 42602496);             // 2.36 MB
  unsigned short* mr0hi = (unsigned short*)(ws + 44961792);  // 64 KB
  unsigned short* mr0lo = (unsigned short*)(ws + 45027328);  // 64 KB
  unsigned short* mr1hi = (unsigned short*)(ws + 45092864);  // 64 KB
  unsigned short* mr1lo = (unsigned short*)(ws + 45158400);  // 64 KB
  unsigned short* fcWhi = (unsigned short*)(ws + 45223936);  // 32 KB
  unsigned short* fcWlo = (unsigned short*)(ws + 45256704);  // 32 KB
  unsigned short* f1hi  = (unsigned short*)(ws + 45289472);  // 128 KB
  unsigned short* f1lo  = (unsigned short*)(ws + 45420544);  // 128 KB
  unsigned short* f2hi  = (unsigned short*)(ws + 45551616);  // 128 KB
  unsigned short* f2lo  = (unsigned short*)(ws + 45682688);  // 128 KB (end 45.81 MB)

  hipMemsetAsync(cntg, 0, 8, stream);

  wsplit_k<<<128, 256, 0, stream>>>(mr0W, mr0hi, mr0lo, 128 * 256);
  wsplit_k<<<128, 256, 0, stream>>>(mr1W, mr1hi, mr1lo, 128 * 256);
  wsplit_k<<<64, 256, 0, stream>>>(fcW, fcWhi, fcWlo, 128 * 128);
  wsplit_k<<<256, 256, 0, stream>>>(f1W, f1hi, f1lo, 512 * 128);
  wsplit_k<<<256, 256, 0, stream>>>(f2W, f2hi, f2lo, 128 * 512);

  norms_concat_k<<<8192, 256, 0, stream>>>(x, y, xyA, norms);
  cbt_k<<<2048, 256, 0, stream>>>(xyA, cbt);
  knn4_k<<<dim3(32, 16), 256, 0, stream>>>(cbt, norms, nbr, cntg, listA, listB, fbl);
  rerank_sl_k<<<256, 256, 0, stream>>>(xyA, norms, fbl, listA, cntg, nbr);
  rerank_fs_k<<<256, 256, 0, stream>>>(xyA, norms, listB, cntg, nbr);

  mrconv2_k<<<1024, 256, 0, stream>>>(xyA, nbr, mr0hi, mr0lo,
      (const float*)d_in[5], (const float*)d_in[6], (const float*)d_in[7],
      (const float*)d_in[8], (const float*)d_in[9], xyB);
  mrconv2_k<<<1024, 256, 0, stream>>>(xyB, nbr, mr1hi, mr1lo,
      (const float*)d_in[11], (const float*)d_in[12], (const float*)d_in[13],
      (const float*)d_in[14], (const float*)d_in[15], xyA);

  fc2_k<<<2048, 256, 0, stream>>>(xyA, fcWhi, fcWlo,
      (const float*)d_in[17], (const float*)d_in[18], (const float*)d_in[19],
      (const float*)d_in[20], (const float*)d_in[21], x, y, xyB);

  ffn2_k<<<2048, 256, 0, stream>>>(xyB,
      f1hi, f1lo, (const float*)d_in[23], (const float*)d_in[24], (const float*)d_in[25],
      (const float*)d_in[26], (const float*)d_in[27],
      f2hi, f2lo, (const float*)d_in[29], (const float*)d_in[30], (const float*)d_in[31],
      (const float*)d_in[32], (const float*)d_in[33],
      xm, ym, (float*)d_out);
}